// Round 1
// baseline (4259.220 us; speedup 1.0000x reference)
//
#include <hip/hip_runtime.h>
#include <cstdint>
#include <cstddef>

// ---------------------------------------------------------------------------
// FluxSingleStreamBlock on MI355X (gfx950), bf16 MFMA pipeline. Round 3:
//  - GEMMs rewritten to the 8-phase 256x256 schedule (HK-style, plain HIP):
//    512 thr / 8 waves (2Mx4N), BK=64, double-buffered 128 KiB LDS,
//    counted s_waitcnt vmcnt(6) at phases 4/8 (never 0 in main loop),
//    s_setprio(1) around each 16-MFMA cluster, XOR LDS swizzle
//    (slot ^= row&7, applied on the global source per rule 21 + on reads),
//    bijective XCD blockIdx swizzle.
//  - K padded to even tile counts: K1P=3200 (NT=50), K2P=15488 (NT=242).
//  - k_attn: setprio around MFMA clusters (T5).
// ws layout (bytes):
//   [0,36864)                 mod (9216 f32): shift|scale|gate
//   A1  : 4608 x 3200 bf16    [x_mod | t1 | 0]
//   Bw  : 21504 x 3200 bf16   [w1 | lu1 | 0] (later overlaid by [w2|lu2|0])
//   qkv : 4608 x 6144 bf16    raw q,k from GEMM1
//   qp  : 24 x 4608 x 128 bf16  (vraw 4608x3072 overlays qp/kp until qkprep)
//   kp  : 24 x 4608 x 128 bf16
//   vt  : 3072 x 4608 bf16    v transposed [h*128+d][l]
//   A2  : 4608 x 15488 bf16   [attn | gelu(mlp) | t2 | 0]
// ---------------------------------------------------------------------------

#define HIDC 3072
#define NHEAD 24
#define HDIM 128
#define SEQ 4608
#define D1 21504     // 3*HID + MLP
#define K1P 3200     // 3072 + 32 lowrank + 96 zeros  (50 K-tiles, even)
#define K2DIM 15360  // HID + MLP
#define K2P 15488    // 15360 + 32 lowrank + 96 zeros (242 K-tiles, even)

typedef __bf16 bf16_t;
typedef __bf16 bf16x2 __attribute__((ext_vector_type(2)));
typedef __bf16 bf16x4 __attribute__((ext_vector_type(4)));
typedef __bf16 bf16x8 __attribute__((ext_vector_type(8)));
typedef float f32x4 __attribute__((ext_vector_type(4)));

__device__ __forceinline__ void gl_lds16(const bf16_t* g, bf16_t* l) {
  __builtin_amdgcn_global_load_lds((__attribute__((address_space(1))) void*)(g),
                                   (__attribute__((address_space(3))) void*)(l),
                                   16, 0, 0);
}

__device__ __forceinline__ void nt_store_bf16(bf16_t* p, bf16_t v) {
  __builtin_nontemporal_store(v, p);
}

__device__ __forceinline__ float gelu_tanh(float v) {
  float c = v + 0.044715f * v * v * v;
  return 0.5f * v * (1.f + tanhf(0.7978845608028654f * c));
}

// ---------------------------------------------------------------------------
// mod = silu(vec) @ mod_w^T + mod_b   (9216 outputs, one wave each)
__global__ __launch_bounds__(256) void k_mod(const float* __restrict__ vec,
                                             const float* __restrict__ mw,
                                             const float* __restrict__ mb,
                                             float* __restrict__ mod) {
  const int lane = threadIdx.x & 63, wid = threadIdx.x >> 6;
  const int j = blockIdx.x * 4 + wid;
  const float* wr = mw + (size_t)j * HIDC;
  float s = 0.f;
  for (int i = lane * 4; i < HIDC; i += 256) {
    float4 w4 = *(const float4*)(wr + i);
    float4 v4 = *(const float4*)(vec + i);
    float a0 = v4.x / (1.f + __expf(-v4.x));
    float a1 = v4.y / (1.f + __expf(-v4.y));
    float a2 = v4.z / (1.f + __expf(-v4.z));
    float a3 = v4.w / (1.f + __expf(-v4.w));
    s += a0 * w4.x + a1 * w4.y + a2 * w4.z + a3 * w4.w;
  }
#pragma unroll
  for (int o = 32; o; o >>= 1) s += __shfl_down(s, o);
  if (lane == 0) mod[j] = s + mb[j];
}

// ---------------------------------------------------------------------------
// LayerNorm + modulation -> A1 (bf16), one block per token row
__global__ __launch_bounds__(256) void k_ln(const float* __restrict__ x,
                                            const float* __restrict__ mod,
                                            bf16_t* __restrict__ A1) {
  const int row = blockIdx.x;
  const int tid = threadIdx.x;
  const float* xr = x + (size_t)row * HIDC;
  float4 v[3];
  float s = 0.f, s2 = 0.f;
#pragma unroll
  for (int it = 0; it < 3; ++it) {
    v[it] = *(const float4*)(xr + (tid + 256 * it) * 4);
    s += v[it].x + v[it].y + v[it].z + v[it].w;
    s2 += v[it].x * v[it].x + v[it].y * v[it].y + v[it].z * v[it].z + v[it].w * v[it].w;
  }
  __shared__ float rbuf[8];
#pragma unroll
  for (int o = 32; o; o >>= 1) { s += __shfl_down(s, o); s2 += __shfl_down(s2, o); }
  const int lane = tid & 63, wid = tid >> 6;
  if (lane == 0) { rbuf[wid] = s; rbuf[4 + wid] = s2; }
  __syncthreads();
  s = rbuf[0] + rbuf[1] + rbuf[2] + rbuf[3];
  s2 = rbuf[4] + rbuf[5] + rbuf[6] + rbuf[7];
  const float mean = s * (1.f / HIDC);
  const float var = s2 * (1.f / HIDC) - mean * mean;
  const float rstd = rsqrtf(var + 1e-6f);
  bf16_t* arow = A1 + (size_t)row * K1P;
#pragma unroll
  for (int it = 0; it < 3; ++it) {
    const int c = (tid + 256 * it) * 4;
    float4 sc = *(const float4*)(mod + HIDC + c);  // scale
    float4 sh = *(const float4*)(mod + c);         // shift
    float y0 = ((v[it].x - mean) * rstd) * (1.f + sc.x) + sh.x;
    float y1 = ((v[it].y - mean) * rstd) * (1.f + sc.y) + sh.y;
    float y2 = ((v[it].z - mean) * rstd) * (1.f + sc.z) + sh.z;
    float y3 = ((v[it].w - mean) * rstd) * (1.f + sc.w) + sh.w;
    bf16x4 o = {(bf16_t)y0, (bf16_t)y1, (bf16_t)y2, (bf16_t)y3};
    *(bf16x4*)(arow + c) = o;
  }
}

// ---------------------------------------------------------------------------
// low-rank projection into A pad columns + zero-fill remaining pad.
// A[row, Kmain+r] = sum_c A[row,c]*ld[r,c]; A[row, Kmain+32 .. Kpad) = 0
__global__ __launch_bounds__(256) void k_lowrank(const bf16_t* __restrict__ Abuf,
                                                 const float* __restrict__ ld,
                                                 bf16_t* __restrict__ Awr,
                                                 int Kmain, int Kpad) {
  const int r = threadIdx.x & 31, slot = threadIdx.x >> 5;
  const int row = blockIdx.x * 8 + slot;
  const bf16_t* a = Abuf + (size_t)row * Kpad;
  const float* lr = ld + (size_t)r * Kmain;
  float s = 0.f;
  for (int c = 0; c < Kmain; c += 8) {
    bf16x8 av = *(const bf16x8*)(a + c);
    float4 l0 = *(const float4*)(lr + c);
    float4 l1 = *(const float4*)(lr + c + 4);
    s += (float)av[0] * l0.x + (float)av[1] * l0.y + (float)av[2] * l0.z + (float)av[3] * l0.w;
    s += (float)av[4] * l1.x + (float)av[5] * l1.y + (float)av[6] * l1.z + (float)av[7] * l1.w;
  }
  bf16_t* w = Awr + (size_t)row * Kpad + Kmain;
  w[r] = (bf16_t)s;
  const int npad = Kpad - Kmain;
  for (int z = 32 + r; z < npad; z += 32) w[z] = (bf16_t)0.f;
}

// ---------------------------------------------------------------------------
// Pack [w | lu | 0] row to bf16 (cached stores: Bw is re-read many times)
__global__ __launch_bounds__(256) void k_convB(const float* __restrict__ w,
                                               const float* __restrict__ lu,
                                               bf16_t* __restrict__ B,
                                               int Kmain, int Kpad) {
  const int row = blockIdx.x;
  const float* wr = w + (size_t)row * Kmain;
  const float* lr = lu + (size_t)row * 32;
  bf16_t* br = B + (size_t)row * Kpad;
  for (int c = threadIdx.x * 4; c < Kpad; c += 1024) {
    float4 v;
    if (c < Kmain) v = *(const float4*)(wr + c);
    else if (c < Kmain + 32) v = *(const float4*)(lr + (c - Kmain));
    else v = make_float4(0.f, 0.f, 0.f, 0.f);
    bf16x4 o = {(bf16_t)v.x, (bf16_t)v.y, (bf16_t)v.z, (bf16_t)v.w};
    *(bf16x4*)(br + c) = o;
  }
}

// ---------------------------------------------------------------------------
// 8-phase 256x256 GEMM core, C = A @ B^T. A:(M x K), B:(N x K) row-major.
// 512 thr / 8 waves; wave (wm = wid>>2, wn = wid&3) owns rows [wm*128,+128),
// cols [wn*64,+64); acc[8][4]. LDS: A,B each [2 buf][256 rows][64 bf16] =
// 128 KiB total, XOR-swizzled: LDS[row][slot] holds global slot (slot^(row&7))
// (8-elem slots). Reads per K-tile (4 phases): {A.mh0+B.nh0 | B.nh1 | A.mh1 | -}
// (B.nh0 and A-halves are held in registers across their 2 consuming phases).
// Stages (one 16KB region/phase) target regions freed in earlier phases:
//   ph1: B(t1).nh1  ph2: A(t2).mh0  ph3: B(t2).nh0  ph4: B(t2).nh1
//   ph5: A(t2).mh1  ph6: A(t3).mh0  ph7: B(t3).nh0  ph8: A(t3).mh1
// vmcnt(6) at ph4/ph8 guarantees everything but the newest 3 regions landed.
// ---------------------------------------------------------------------------

#define FBAR do { asm volatile("" ::: "memory"); __builtin_amdgcn_s_barrier(); \
                  asm volatile("" ::: "memory"); } while (0)
#define VMW(n) asm volatile("s_waitcnt vmcnt(" #n ")" ::: "memory")

// stage A region mh of tile t: rows {mh*64+[0,64)} U {128+mh*64+[0,64)}
#define STA_(t, mh) do { \
  _Pragma("unroll") for (int h_ = 0; h_ < 2; ++h_) { \
    const int row_ = h_ * 128 + (mh) * 64 + wid * 8 + srow; \
    gl_lds16(Ag + (size_t)(t) * 64 + (size_t)row_ * K + ((sslot ^ srow) * 8), \
             As + (((t) & 1) * 16384) + row_ * 64 + sslot * 8); \
  } } while (0)

// stage B region nh of tile t: rows {wn*64+nh*32+[0,32)} for wn=0..3
#define STB_(t, nh) do { \
  _Pragma("unroll") for (int h_ = 0; h_ < 2; ++h_) { \
    const int row_ = h_ * 128 + ((wid >> 2) * 64) + (nh) * 32 + (wid & 3) * 8 + srow; \
    gl_lds16(Bg + (size_t)(t) * 64 + (size_t)row_ * K + ((sslot ^ srow) * 8), \
             Bs + (((t) & 1) * 16384) + row_ * 64 + sslot * 8); \
  } } while (0)

#define FRA(buf, mrep, kk) \
  (*(const bf16x8*)(As + (buf) * 16384 + (wm * 128 + (mrep) * 16 + m16) * 64 + \
                    ((((kk) * 4 + quad) ^ m7) * 8)))
#define FRB(buf, nrep, kk) \
  (*(const bf16x8*)(Bs + (buf) * 16384 + (wn * 64 + (nrep) * 16 + m16) * 64 + \
                    ((((kk) * 4 + quad) ^ m7) * 8)))

#define LDA4(dst, buf, mh) do { \
  _Pragma("unroll") for (int m4_ = 0; m4_ < 4; ++m4_) { \
    dst[m4_][0] = FRA(buf, (mh) * 4 + m4_, 0); \
    dst[m4_][1] = FRA(buf, (mh) * 4 + m4_, 1); } } while (0)

#define LDB2(dst, buf, nh) do { \
  _Pragma("unroll") for (int n2_ = 0; n2_ < 2; ++n2_) { \
    dst[n2_][0] = FRB(buf, (nh) * 2 + n2_, 0); \
    dst[n2_][1] = FRB(buf, (nh) * 2 + n2_, 1); } } while (0)

#define MMAQ(mh, nh, af, bfm) do { \
  __builtin_amdgcn_s_setprio(1); \
  _Pragma("unroll") for (int kk_ = 0; kk_ < 2; ++kk_) \
  _Pragma("unroll") for (int m4_ = 0; m4_ < 4; ++m4_) \
  _Pragma("unroll") for (int n2_ = 0; n2_ < 2; ++n2_) \
    acc[(mh) * 4 + m4_][(nh) * 2 + n2_] = __builtin_amdgcn_mfma_f32_16x16x32_bf16( \
        af[m4_][kk_], bfm[n2_][kk_], acc[(mh) * 4 + m4_][(nh) * 2 + n2_], 0, 0, 0); \
  __builtin_amdgcn_s_setprio(0); \
} while (0)

__device__ __forceinline__ void gemm8_core(const bf16_t* __restrict__ A,
                                           const bf16_t* __restrict__ B,
                                           const int K, const int tileM, const int tileN,
                                           bf16_t* __restrict__ As, bf16_t* __restrict__ Bs,
                                           f32x4 acc[8][4]) {
  const int tid = threadIdx.x, lane = tid & 63, wid = tid >> 6;
  const int wm = wid >> 2, wn = wid & 3;
  const int quad = lane >> 4, m16 = lane & 15, m7 = lane & 7;
  const int srow = lane >> 3, sslot = lane & 7;
  const f32x4 fz = {0.f, 0.f, 0.f, 0.f};
#pragma unroll
  for (int m = 0; m < 8; ++m)
#pragma unroll
    for (int n = 0; n < 4; ++n) acc[m][n] = fz;
  const bf16_t* Ag = A + (size_t)tileM * K;
  const bf16_t* Bg = B + (size_t)tileN * K;
  const int NT = K >> 6;   // K-tiles (even)
  const int NI = NT >> 1;  // iterations (2 K-tiles each)

  bf16x8 afA[4][2], afB[4][2], bfL[2][2], bfH[2][2];

  // prologue: tile0 complete (8 loads), tile1 {A.mh0, B.nh0, A.mh1} (6 loads);
  // tile1.B.nh1 is staged at iter0 ph1 per the steady-state pattern.
  STA_(0, 0); STA_(0, 1); STB_(0, 0); STB_(0, 1);
  STA_(1, 0); STB_(1, 0); STA_(1, 1);
  VMW(6);  // tile0's 8 loads landed; tile1's 6 in flight
  FBAR;

  for (int i = 0; i < NI - 1; ++i) {
    const int t1 = 2 * i + 1, t2 = 2 * i + 2, t3 = 2 * i + 3;
    // ph1: reads A(t0).mh0 + B(t0).nh0
    LDA4(afA, 0, 0); LDB2(bfL, 0, 0);
    STB_(t1, 1);
    FBAR;
    MMAQ(0, 0, afA, bfL);
    FBAR;
    // ph2: reads B(t0).nh1
    LDB2(bfH, 0, 1);
    STA_(t2, 0);
    FBAR;
    MMAQ(0, 1, afA, bfH);
    FBAR;
    // ph3: reads A(t0).mh1
    LDA4(afB, 0, 1);
    STB_(t2, 0);
    FBAR;
    MMAQ(1, 1, afB, bfH);
    FBAR;
    // ph4: no reads (afB, bfL live in regs)
    STB_(t2, 1);
    VMW(6);  // everything up to ph1's stage landed -> tile t1 ready
    FBAR;
    MMAQ(1, 0, afB, bfL);
    FBAR;
    // ph5: reads A(t1).mh0 + B(t1).nh0
    LDA4(afA, 1, 0); LDB2(bfL, 1, 0);
    STA_(t2, 1);
    FBAR;
    MMAQ(0, 0, afA, bfL);
    FBAR;
    // ph6: reads B(t1).nh1
    LDB2(bfH, 1, 1);
    STA_(t3, 0);
    FBAR;
    MMAQ(0, 1, afA, bfH);
    FBAR;
    // ph7: reads A(t1).mh1
    LDA4(afB, 1, 1);
    STB_(t3, 0);
    FBAR;
    MMAQ(1, 1, afB, bfH);
    FBAR;
    // ph8: no reads
    STA_(t3, 1);
    VMW(6);  // everything up to ph5's stage landed -> tile t2 ready
    FBAR;
    MMAQ(1, 0, afB, bfL);
    FBAR;
  }
  // peeled last iteration (tiles NT-2 / NT-1): only ph1's stage remains
  {
    LDA4(afA, 0, 0); LDB2(bfL, 0, 0);
    STB_(NT - 1, 1);
    FBAR;
    MMAQ(0, 0, afA, bfL);
    FBAR;
    LDB2(bfH, 0, 1);
    FBAR;
    MMAQ(0, 1, afA, bfH);
    FBAR;
    LDA4(afB, 0, 1);
    FBAR;
    MMAQ(1, 1, afB, bfH);
    FBAR;
    VMW(0);  // drain: tile NT-1 fully landed
    FBAR;
    MMAQ(1, 0, afB, bfL);
    FBAR;
    LDA4(afA, 1, 0); LDB2(bfL, 1, 0);
    FBAR;
    MMAQ(0, 0, afA, bfL);
    FBAR;
    LDB2(bfH, 1, 1);
    FBAR;
    MMAQ(0, 1, afA, bfH);
    FBAR;
    LDA4(afB, 1, 1);
    FBAR;
    MMAQ(1, 1, afB, bfH);
    FBAR;
    MMAQ(1, 0, afB, bfL);
  }
}

// GEMM1: A1(4608x3200) @ B1(21504x3200)^T + b1 -> qkv / vraw / gelu->A2
__global__ __launch_bounds__(512, 2) void k_gemm1(const bf16_t* __restrict__ A1,
                                                  const bf16_t* __restrict__ B1,
                                                  const float* __restrict__ b1,
                                                  bf16_t* __restrict__ qkv,
                                                  bf16_t* __restrict__ vraw,
                                                  bf16_t* __restrict__ A2) {
  __shared__ __align__(16) bf16_t As[2 * 256 * 64];
  __shared__ __align__(16) bf16_t Bs[2 * 256 * 64];
  f32x4 acc[8][4];
  const int nwg = 18 * 84;
  const int b = blockIdx.x;
  const int swz = (b & 7) * (nwg >> 3) + (b >> 3);  // bijective XCD swizzle
  const int tileM = (swz % 18) * 256, tileN = (swz / 18) * 256;
  gemm8_core(A1, B1, K1P, tileM, tileN, As, Bs, acc);
  const int lane = threadIdx.x & 63, wid = threadIdx.x >> 6;
  const int wm = wid >> 2, wn = wid & 3;
  const int quad = lane >> 4, m16 = lane & 15;
#pragma unroll
  for (int m = 0; m < 8; ++m) {
    const int row0 = tileM + wm * 128 + m * 16 + quad * 4;
#pragma unroll
    for (int n = 0; n < 4; ++n) {
      const int col = tileN + wn * 64 + n * 16 + m16;
      const float bias = b1[col];
#pragma unroll
      for (int r = 0; r < 4; ++r) {
        const float v = acc[m][n][r] + bias;
        const int rr = row0 + r;
        if (col < 6144) {
          nt_store_bf16(qkv + (size_t)rr * 6144 + col, (bf16_t)v);
        } else if (col < 9216) {
          nt_store_bf16(vraw + (size_t)rr * HIDC + (col - 6144), (bf16_t)v);
        } else {
          nt_store_bf16(A2 + (size_t)rr * K2P + HIDC + (col - 9216), (bf16_t)gelu_tanh(v));
        }
      }
    }
  }
}

// GEMM2: A2(4608x15488) @ B2(3072x15488)^T + b2, out = x + gate*val (fp32)
__global__ __launch_bounds__(512, 2) void k_gemm2(const bf16_t* __restrict__ A2,
                                                  const bf16_t* __restrict__ B2,
                                                  const float* __restrict__ b2,
                                                  const float* __restrict__ x,
                                                  const float* __restrict__ mod,
                                                  float* __restrict__ out) {
  __shared__ __align__(16) bf16_t As[2 * 256 * 64];
  __shared__ __align__(16) bf16_t Bs[2 * 256 * 64];
  f32x4 acc[8][4];
  const int nwg = 18 * 12;
  const int b = blockIdx.x;
  const int swz = (b & 7) * (nwg >> 3) + (b >> 3);
  const int tileM = (swz % 18) * 256, tileN = (swz / 18) * 256;
  gemm8_core(A2, B2, K2P, tileM, tileN, As, Bs, acc);
  const int lane = threadIdx.x & 63, wid = threadIdx.x >> 6;
  const int wm = wid >> 2, wn = wid & 3;
  const int quad = lane >> 4, m16 = lane & 15;
#pragma unroll
  for (int m = 0; m < 8; ++m) {
    const int row0 = tileM + wm * 128 + m * 16 + quad * 4;
#pragma unroll
    for (int n = 0; n < 4; ++n) {
      const int col = tileN + wn * 64 + n * 16 + m16;
      const float bias = b2[col];
      const float gate = mod[2 * HIDC + col];
#pragma unroll
      for (int r = 0; r < 4; ++r) {
        const int rr = row0 + r;
        const float v = acc[m][n][r] + bias;
        __builtin_nontemporal_store(x[(size_t)rr * HIDC + col] + gate * v,
                                    out + (size_t)rr * HIDC + col);
      }
    }
  }
}

// ---------------------------------------------------------------------------
// v transpose: vraw (4608 x 3072, [l][h*128+d]) -> vt (3072 x 4608, [h*128+d][l])
__global__ __launch_bounds__(256) void k_vtrans(const bf16_t* __restrict__ vraw,
                                                bf16_t* __restrict__ vt) {
  __shared__ bf16_t Ts[64][68];
  const int tid = threadIdx.x;
  const int l0 = (blockIdx.x % 72) * 64, c0 = (blockIdx.x / 72) * 64;
#pragma unroll
  for (int s = 0; s < 2; ++s) {
    const int idx = s * 256 + tid;
    const int lrow = idx >> 3, c8 = (idx & 7) * 8;
    bf16x8 v = *(const bf16x8*)(vraw + (size_t)(l0 + lrow) * HIDC + c0 + c8);
#pragma unroll
    for (int e = 0; e < 8; ++e) Ts[c8 + e][lrow] = v[e];
  }
  __syncthreads();
#pragma unroll
  for (int s = 0; s < 2; ++s) {
    const int idx = s * 256 + tid;
    const int drow = idx >> 3, l8 = (idx & 7) * 8;
    bf16x8 v;
#pragma unroll
    for (int e = 0; e < 8; ++e) v[e] = Ts[drow][l8 + e];
    *(bf16x8*)(vt + (size_t)(c0 + drow) * SEQ + l0 + l8) = v;
  }
}

// ---------------------------------------------------------------------------
// RMSNorm + RoPE + repack: one wave per (token, head, q-or-k)
__global__ __launch_bounds__(256) void k_qkprep(const bf16_t* __restrict__ qkv,
                                                const float* __restrict__ pe,
                                                const float* __restrict__ rqw,
                                                const float* __restrict__ rkw,
                                                bf16_t* __restrict__ qp,
                                                bf16_t* __restrict__ kp) {
  const int lane = threadIdx.x & 63, wid = threadIdx.x >> 6;
  int g = blockIdx.x * 4 + wid;
  const int which = (g >= SEQ * NHEAD) ? 1 : 0;
  g -= which * SEQ * NHEAD;
  const int l = g / NHEAD, h = g % NHEAD;
  const int d0 = lane * 2;
  const bf16_t* src = qkv + (size_t)l * 6144 + which * HIDC + h * HDIM + d0;
  bf16x2 xv = *(const bf16x2*)src;
  float x0 = (float)xv[0], x1 = (float)xv[1];
  float ss = x0 * x0 + x1 * x1;
#pragma unroll
  for (int o = 32; o; o >>= 1) ss += __shfl_xor(ss, o);
  const float rstd = rsqrtf(ss * (1.f / HDIM) + 1e-6f);
  const float* wv = which ? rkw : rqw;
  x0 *= rstd * wv[d0];
  x1 *= rstd * wv[d0 + 1];
  const float4 rr = *(const float4*)(pe + (size_t)l * 256 + lane * 4);  // r00 r01 r10 r11
  bf16x2 o2 = {(bf16_t)(rr.x * x0 + rr.y * x1), (bf16_t)(rr.z * x0 + rr.w * x1)};
  bf16_t* dst = (which ? kp : qp) + (size_t)(h * SEQ + l) * HDIM + d0;
  *(bf16x2*)dst = o2;
}

// ---------------------------------------------------------------------------
// Flash attention: block = (head, 64 q-rows), wave = 16 q-rows, K/V tiles of 64
__global__ __launch_bounds__(256, 2) void k_attn(const bf16_t* __restrict__ qp,
                                                 const bf16_t* __restrict__ kp,
                                                 const bf16_t* __restrict__ vt,
                                                 bf16_t* __restrict__ A2) {
  __shared__ __align__(16) bf16_t Ks[16 * 64 * 8];   // [dchunk16][key64][8]
  __shared__ __align__(16) bf16_t Vs[8 * 128 * 8];   // [kchunk8][d128][8]
  __shared__ __align__(16) bf16_t Ps[4][1024];       // per wave [kchunk8][row16][8]
  const float SM_SCALE = 0.08838834764831845f;       // 1/sqrt(128)
  const int tid = threadIdx.x, lane = tid & 63, wid = tid >> 6;
  const int quad = lane >> 4, m16 = lane & 15;
  const int h = blockIdx.x / 72, qt = blockIdx.x % 72;
  const int qbase = qt * 64 + wid * 16;
  bf16x8 qf[4];
  {
    const bf16_t* qr = qp + (size_t)(h * SEQ + qbase + m16) * HDIM + quad * 8;
#pragma unroll
    for (int c = 0; c < 4; ++c) qf[c] = *(const bf16x8*)(qr + c * 32);
  }
  const f32x4 fzero = {0.f, 0.f, 0.f, 0.f};
  f32x4 oacc[8];
#pragma unroll
  for (int j2 = 0; j2 < 8; ++j2) oacc[j2] = fzero;
  float mrun[4] = {-1e30f, -1e30f, -1e30f, -1e30f};
  float lrun[4] = {0.f, 0.f, 0.f, 0.f};
  const bf16_t* kg = kp + (size_t)h * SEQ * HDIM;
  const bf16_t* vg = vt + (size_t)h * HDIM * SEQ;
  for (int kt = 0; kt < SEQ; kt += 64) {
    __syncthreads();
#pragma unroll
    for (int s = 0; s < 4; ++s) {
      int o = s * 256 + tid;
      gl_lds16(kg + (size_t)(kt + (o & 63)) * HDIM + (o >> 6) * 8, Ks + (size_t)o * 8);
    }
#pragma unroll
    for (int s = 0; s < 4; ++s) {
      int o = s * 256 + tid;
      gl_lds16(vg + (size_t)(o & 127) * SEQ + kt + (o >> 7) * 8, Vs + (size_t)o * 8);
    }
    __syncthreads();
    f32x4 st[4];
#pragma unroll
    for (int jj = 0; jj < 4; ++jj) st[jj] = fzero;
    __builtin_amdgcn_s_setprio(1);
#pragma unroll
    for (int c = 0; c < 4; ++c)
#pragma unroll
      for (int jj = 0; jj < 4; ++jj) {
        bf16x8 kf = *(const bf16x8*)(Ks + (size_t)((c * 4 + quad) * 64 + jj * 16 + m16) * 8);
        st[jj] = __builtin_amdgcn_mfma_f32_16x16x32_bf16(qf[c], kf, st[jj], 0, 0, 0);
      }
    __builtin_amdgcn_s_setprio(0);
    float mnew[4], alpha[4], rsum[4];
#pragma unroll
    for (int r = 0; r < 4; ++r) {
      float mx = fmaxf(fmaxf(st[0][r], st[1][r]), fmaxf(st[2][r], st[3][r]));
#pragma unroll
      for (int o = 1; o < 16; o <<= 1) mx = fmaxf(mx, __shfl_xor(mx, o));
      mx *= SM_SCALE;
      float mn = fmaxf(mrun[r], mx);
      alpha[r] = __expf(mrun[r] - mn);
      mnew[r] = mn;
      mrun[r] = mn;
      rsum[r] = 0.f;
    }
#pragma unroll
    for (int jj = 0; jj < 4; ++jj) {
#pragma unroll
      for (int r = 0; r < 4; ++r) {
        float p = __expf(st[jj][r] * SM_SCALE - mnew[r]);
        rsum[r] += p;
        Ps[wid][(size_t)((jj * 2 + (m16 >> 3)) * 16 + quad * 4 + r) * 8 + (m16 & 7)] = (bf16_t)p;
      }
    }
#pragma unroll
    for (int r = 0; r < 4; ++r) {
      float t = rsum[r];
#pragma unroll
      for (int o = 1; o < 16; o <<= 1) t += __shfl_xor(t, o);
      lrun[r] = lrun[r] * alpha[r] + t;
    }
#pragma unroll
    for (int j2 = 0; j2 < 8; ++j2)
#pragma unroll
      for (int r = 0; r < 4; ++r) oacc[j2][r] *= alpha[r];
    __builtin_amdgcn_s_setprio(1);
#pragma unroll
    for (int kc2 = 0; kc2 < 2; ++kc2) {
      bf16x8 pf = *(const bf16x8*)(&Ps[wid][(size_t)((kc2 * 4 + quad) * 16 + m16) * 8]);
#pragma unroll
      for (int j2 = 0; j2 < 8; ++j2) {
        bf16x8 vf = *(const bf16x8*)(Vs + (size_t)((kc2 * 4 + quad) * 128 + j2 * 16 + m16) * 8);
        oacc[j2] = __builtin_amdgcn_mfma_f32_16x16x32_bf16(pf, vf, oacc[j2], 0, 0, 0);
      }
    }
    __builtin_amdgcn_s_setprio(0);
  }
#pragma unroll
  for (int j2 = 0; j2 < 8; ++j2) {
#pragma unroll
    for (int r = 0; r < 4; ++r) {
      const int row = qbase + quad * 4 + r;
      const int col = h * HDIM + j2 * 16 + m16;
      nt_store_bf16(A2 + (size_t)row * K2P + col, (bf16_t)(oacc[j2][r] / lrun[r]));
    }
  }
}

// ---------------------------------------------------------------------------
extern "C" void kernel_launch(void* const* d_in, const int* in_sizes, int n_in,
                              void* d_out, int out_size, void* d_ws, size_t ws_size,
                              hipStream_t stream) {
  const float* x = (const float*)d_in[0];
  const float* vec = (const float*)d_in[1];
  const float* pe = (const float*)d_in[2];
  const float* mod_w = (const float*)d_in[3];
  const float* mod_b = (const float*)d_in[4];
  const float* w1 = (const float*)d_in[5];
  const float* b1 = (const float*)d_in[6];
  const float* ld1 = (const float*)d_in[7];
  const float* lu1 = (const float*)d_in[8];
  const float* w2 = (const float*)d_in[9];
  const float* b2 = (const float*)d_in[10];
  const float* ld2 = (const float*)d_in[11];
  const float* lu2 = (const float*)d_in[12];
  const float* rqw = (const float*)d_in[13];
  const float* rkw = (const float*)d_in[14];
  float* out = (float*)d_out;
  char* ws = (char*)d_ws;

  const size_t OFF_A1 = 36864;
  const size_t OFF_B = OFF_A1 + (size_t)SEQ * K1P * 2;
  const size_t OFF_QKV = OFF_B + (size_t)D1 * K1P * 2;
  const size_t OFF_QP = OFF_QKV + (size_t)SEQ * 6144 * 2;
  const size_t OFF_KP = OFF_QP + (size_t)NHEAD * SEQ * HDIM * 2;
  const size_t OFF_VT = OFF_KP + (size_t)NHEAD * SEQ * HDIM * 2;
  const size_t OFF_A2 = OFF_VT + (size_t)NHEAD * SEQ * HDIM * 2;

  float* mod = (float*)ws;
  bf16_t* A1 = (bf16_t*)(ws + OFF_A1);
  bf16_t* Bw = (bf16_t*)(ws + OFF_B);
  bf16_t* qkv = (bf16_t*)(ws + OFF_QKV);
  bf16_t* qp = (bf16_t*)(ws + OFF_QP);
  bf16_t* vraw = (bf16_t*)(ws + OFF_QP);  // overlays qp/kp until k_qkprep runs
  bf16_t* kp = (bf16_t*)(ws + OFF_KP);
  bf16_t* vt = (bf16_t*)(ws + OFF_VT);
  bf16_t* A2 = (bf16_t*)(ws + OFF_A2);

  k_convB<<<D1, 256, 0, stream>>>(w1, lu1, Bw, HIDC, K1P);
  k_mod<<<9216 / 4, 256, 0, stream>>>(vec, mod_w, mod_b, mod);
  k_ln<<<SEQ, 256, 0, stream>>>(x, mod, A1);
  k_lowrank<<<SEQ / 8, 256, 0, stream>>>(A1, ld1, A1, HIDC, K1P);
  k_gemm1<<<18 * 84, 512, 0, stream>>>(A1, Bw, b1, qkv, vraw, A2);
  k_vtrans<<<72 * 48, 256, 0, stream>>>(vraw, vt);
  k_qkprep<<<SEQ * NHEAD * 2 / 4, 256, 0, stream>>>(qkv, pe, rqw, rkw, qp, kp);
  k_attn<<<NHEAD * 72, 256, 0, stream>>>(qp, kp, vt, A2);
  k_convB<<<HIDC, 256, 0, stream>>>(w2, lu2, Bw, K2DIM, K2P);
  k_lowrank<<<SEQ / 8, 256, 0, stream>>>(A2, ld2, A2, K2DIM, K2P);
  k_gemm2<<<18 * 12, 512, 0, stream>>>(A2, Bw, b2, x, mod, out);
}

// Round 2
// 2611.118 us; speedup vs baseline: 1.6312x; 1.6312x over previous
//
#include <hip/hip_runtime.h>
#include <cstdint>
#include <cstddef>

// ---------------------------------------------------------------------------
// FluxSingleStreamBlock on MI355X (gfx950), bf16 MFMA pipeline. Round 4:
//  - k_lowrank (2x ~1450us, dominant cost in R3 profile: MfmaUtil 0, VALU 11%,
//    HBM 0.7%, latency-bound 32x-redundant reads) replaced by split-K MFMA
//    skinny GEMM: k_convB(ld->bf16) + k_lr1 (72x16 blocks, 16x16x32 MFMA,
//    fp32 partials) + k_lr2 (reduce 16 partials -> bf16 pad cols + zero fill).
//    Scratch (ldb 1MB, tpart 9.4MB) overlays the dead qkv region.
//  - GEMMs: 8-phase 256x256 schedule (verified R3), unchanged.
//  - attn: unchanged.
// ws layout (bytes):
//   [0,36864)                 mod (9216 f32): shift|scale|gate
//   A1  : 4608 x 3200 bf16    [x_mod | t1 | 0]
//   Bw  : 21504 x 3200 bf16   [w1 | lu1 | 0] (later overlaid by [w2|lu2|0])
//   qkv : 4608 x 6144 bf16    raw q,k from GEMM1 (ldb+tpart overlay when dead)
//   qp  : 24 x 4608 x 128 bf16  (vraw 4608x3072 overlays qp/kp until qkprep)
//   kp  : 24 x 4608 x 128 bf16
//   vt  : 3072 x 4608 bf16    v transposed [h*128+d][l]
//   A2  : 4608 x 15488 bf16   [attn | gelu(mlp) | t2 | 0]
// ---------------------------------------------------------------------------

#define HIDC 3072
#define NHEAD 24
#define HDIM 128
#define SEQ 4608
#define D1 21504     // 3*HID + MLP
#define K1P 3200     // 3072 + 32 lowrank + 96 zeros  (50 K-tiles, even)
#define K2DIM 15360  // HID + MLP
#define K2P 15488    // 15360 + 32 lowrank + 96 zeros (242 K-tiles, even)
#define LRKS 16      // low-rank split-K factor

typedef __bf16 bf16_t;
typedef __bf16 bf16x2 __attribute__((ext_vector_type(2)));
typedef __bf16 bf16x4 __attribute__((ext_vector_type(4)));
typedef __bf16 bf16x8 __attribute__((ext_vector_type(8)));
typedef float f32x4 __attribute__((ext_vector_type(4)));

__device__ __forceinline__ void gl_lds16(const bf16_t* g, bf16_t* l) {
  __builtin_amdgcn_global_load_lds((__attribute__((address_space(1))) void*)(g),
                                   (__attribute__((address_space(3))) void*)(l),
                                   16, 0, 0);
}

__device__ __forceinline__ void nt_store_bf16(bf16_t* p, bf16_t v) {
  __builtin_nontemporal_store(v, p);
}

__device__ __forceinline__ float gelu_tanh(float v) {
  float c = v + 0.044715f * v * v * v;
  return 0.5f * v * (1.f + tanhf(0.7978845608028654f * c));
}

// ---------------------------------------------------------------------------
// mod = silu(vec) @ mod_w^T + mod_b   (9216 outputs, one wave each)
__global__ __launch_bounds__(256) void k_mod(const float* __restrict__ vec,
                                             const float* __restrict__ mw,
                                             const float* __restrict__ mb,
                                             float* __restrict__ mod) {
  const int lane = threadIdx.x & 63, wid = threadIdx.x >> 6;
  const int j = blockIdx.x * 4 + wid;
  const float* wr = mw + (size_t)j * HIDC;
  float s = 0.f;
  for (int i = lane * 4; i < HIDC; i += 256) {
    float4 w4 = *(const float4*)(wr + i);
    float4 v4 = *(const float4*)(vec + i);
    float a0 = v4.x / (1.f + __expf(-v4.x));
    float a1 = v4.y / (1.f + __expf(-v4.y));
    float a2 = v4.z / (1.f + __expf(-v4.z));
    float a3 = v4.w / (1.f + __expf(-v4.w));
    s += a0 * w4.x + a1 * w4.y + a2 * w4.z + a3 * w4.w;
  }
#pragma unroll
  for (int o = 32; o; o >>= 1) s += __shfl_down(s, o);
  if (lane == 0) mod[j] = s + mb[j];
}

// ---------------------------------------------------------------------------
// LayerNorm + modulation -> A1 (bf16), one block per token row
__global__ __launch_bounds__(256) void k_ln(const float* __restrict__ x,
                                            const float* __restrict__ mod,
                                            bf16_t* __restrict__ A1) {
  const int row = blockIdx.x;
  const int tid = threadIdx.x;
  const float* xr = x + (size_t)row * HIDC;
  float4 v[3];
  float s = 0.f, s2 = 0.f;
#pragma unroll
  for (int it = 0; it < 3; ++it) {
    v[it] = *(const float4*)(xr + (tid + 256 * it) * 4);
    s += v[it].x + v[it].y + v[it].z + v[it].w;
    s2 += v[it].x * v[it].x + v[it].y * v[it].y + v[it].z * v[it].z + v[it].w * v[it].w;
  }
  __shared__ float rbuf[8];
#pragma unroll
  for (int o = 32; o; o >>= 1) { s += __shfl_down(s, o); s2 += __shfl_down(s2, o); }
  const int lane = tid & 63, wid = tid >> 6;
  if (lane == 0) { rbuf[wid] = s; rbuf[4 + wid] = s2; }
  __syncthreads();
  s = rbuf[0] + rbuf[1] + rbuf[2] + rbuf[3];
  s2 = rbuf[4] + rbuf[5] + rbuf[6] + rbuf[7];
  const float mean = s * (1.f / HIDC);
  const float var = s2 * (1.f / HIDC) - mean * mean;
  const float rstd = rsqrtf(var + 1e-6f);
  bf16_t* arow = A1 + (size_t)row * K1P;
#pragma unroll
  for (int it = 0; it < 3; ++it) {
    const int c = (tid + 256 * it) * 4;
    float4 sc = *(const float4*)(mod + HIDC + c);  // scale
    float4 sh = *(const float4*)(mod + c);         // shift
    float y0 = ((v[it].x - mean) * rstd) * (1.f + sc.x) + sh.x;
    float y1 = ((v[it].y - mean) * rstd) * (1.f + sc.y) + sh.y;
    float y2 = ((v[it].z - mean) * rstd) * (1.f + sc.z) + sh.z;
    float y3 = ((v[it].w - mean) * rstd) * (1.f + sc.w) + sh.w;
    bf16x4 o = {(bf16_t)y0, (bf16_t)y1, (bf16_t)y2, (bf16_t)y3};
    *(bf16x4*)(arow + c) = o;
  }
}

// ---------------------------------------------------------------------------
// low-rank stage 1: tpart[ks] = A[:, ks*KC:(ks+1)*KC] @ ldb[:, same]^T (fp32)
// grid = 72 M-tiles x LRKS k-splits, 256 thr / 4 waves, wave = 16 rows x 32 ranks
__global__ __launch_bounds__(256) void k_lr1(const bf16_t* __restrict__ Abuf,
                                             const bf16_t* __restrict__ ldb,
                                             float* __restrict__ tpart,
                                             int Kmain, int Kpad, int KC) {
  const int tid = threadIdx.x, lane = tid & 63, w = tid >> 6;
  const int quad = lane >> 4, m16 = lane & 15;
  const int mt = blockIdx.x % 72, ks = blockIdx.x / 72;
  const int row0 = mt * 64 + w * 16;
  const int k0 = ks * KC;
  const f32x4 fz = {0.f, 0.f, 0.f, 0.f};
  f32x4 acc0 = fz, acc1 = fz;
  const bf16_t* ar = Abuf + (size_t)(row0 + m16) * Kpad + k0 + quad * 8;
  const bf16_t* b0 = ldb + (size_t)m16 * Kmain + k0 + quad * 8;
  const bf16_t* b1 = ldb + (size_t)(16 + m16) * Kmain + k0 + quad * 8;
  for (int kt = 0; kt < KC; kt += 32) {
    bf16x8 af = *(const bf16x8*)(ar + kt);
    bf16x8 f0 = *(const bf16x8*)(b0 + kt);
    bf16x8 f1 = *(const bf16x8*)(b1 + kt);
    acc0 = __builtin_amdgcn_mfma_f32_16x16x32_bf16(af, f0, acc0, 0, 0, 0);
    acc1 = __builtin_amdgcn_mfma_f32_16x16x32_bf16(af, f1, acc1, 0, 0, 0);
  }
  float* tp = tpart + (size_t)ks * SEQ * 32;
#pragma unroll
  for (int r = 0; r < 4; ++r) {
    const int row = row0 + quad * 4 + r;
    tp[(size_t)row * 32 + m16] = acc0[r];
    tp[(size_t)row * 32 + 16 + m16] = acc1[r];
  }
}

// low-rank stage 2: sum LRKS partials -> bf16 pad cols, zero-fill rest of pad
__global__ __launch_bounds__(256) void k_lr2(const float* __restrict__ tpart,
                                             bf16_t* __restrict__ Awr,
                                             int Kmain, int Kpad) {
  const int rank = threadIdx.x & 31, slot = threadIdx.x >> 5;
  const int row = blockIdx.x * 8 + slot;
  float s = 0.f;
#pragma unroll
  for (int ks = 0; ks < LRKS; ++ks)
    s += tpart[((size_t)ks * SEQ + row) * 32 + rank];
  bf16_t* wptr = Awr + (size_t)row * Kpad + Kmain;
  wptr[rank] = (bf16_t)s;
  const int npad = Kpad - Kmain;
  for (int z = 32 + rank; z < npad; z += 32) wptr[z] = (bf16_t)0.f;
}

// ---------------------------------------------------------------------------
// Pack [w | lu | 0] row to bf16 (cached stores: Bw is re-read many times).
// Also reused with Kpad==Kmain to convert ld (32 x Kmain fp32) -> bf16.
__global__ __launch_bounds__(256) void k_convB(const float* __restrict__ w,
                                               const float* __restrict__ lu,
                                               bf16_t* __restrict__ B,
                                               int Kmain, int Kpad) {
  const int row = blockIdx.x;
  const float* wr = w + (size_t)row * Kmain;
  const float* lr = lu + (size_t)row * 32;
  bf16_t* br = B + (size_t)row * Kpad;
  for (int c = threadIdx.x * 4; c < Kpad; c += 1024) {
    float4 v;
    if (c < Kmain) v = *(const float4*)(wr + c);
    else if (c < Kmain + 32) v = *(const float4*)(lr + (c - Kmain));
    else v = make_float4(0.f, 0.f, 0.f, 0.f);
    bf16x4 o = {(bf16_t)v.x, (bf16_t)v.y, (bf16_t)v.z, (bf16_t)v.w};
    *(bf16x4*)(br + c) = o;
  }
}

// ---------------------------------------------------------------------------
// 8-phase 256x256 GEMM core, C = A @ B^T. A:(M x K), B:(N x K) row-major.
// 512 thr / 8 waves; wave (wm = wid>>2, wn = wid&3) owns rows [wm*128,+128),
// cols [wn*64,+64); acc[8][4]. LDS: A,B each [2 buf][256 rows][64 bf16] =
// 128 KiB total, XOR-swizzled: LDS[row][slot] holds global slot (slot^(row&7))
// (8-elem slots). Reads per K-tile (4 phases): {A.mh0+B.nh0 | B.nh1 | A.mh1 | -}
// (B.nh0 and A-halves are held in registers across their 2 consuming phases).
// Stages (one 16KB region/phase) target regions freed in earlier phases:
//   ph1: B(t1).nh1  ph2: A(t2).mh0  ph3: B(t2).nh0  ph4: B(t2).nh1
//   ph5: A(t2).mh1  ph6: A(t3).mh0  ph7: B(t3).nh0  ph8: A(t3).mh1
// vmcnt(6) at ph4/ph8 guarantees everything but the newest 3 regions landed.
// ---------------------------------------------------------------------------

#define FBAR do { asm volatile("" ::: "memory"); __builtin_amdgcn_s_barrier(); \
                  asm volatile("" ::: "memory"); } while (0)
#define VMW(n) asm volatile("s_waitcnt vmcnt(" #n ")" ::: "memory")

// stage A region mh of tile t: rows {mh*64+[0,64)} U {128+mh*64+[0,64)}
#define STA_(t, mh) do { \
  _Pragma("unroll") for (int h_ = 0; h_ < 2; ++h_) { \
    const int row_ = h_ * 128 + (mh) * 64 + wid * 8 + srow; \
    gl_lds16(Ag + (size_t)(t) * 64 + (size_t)row_ * K + ((sslot ^ srow) * 8), \
             As + (((t) & 1) * 16384) + row_ * 64 + sslot * 8); \
  } } while (0)

// stage B region nh of tile t: rows {wn*64+nh*32+[0,32)} for wn=0..3
#define STB_(t, nh) do { \
  _Pragma("unroll") for (int h_ = 0; h_ < 2; ++h_) { \
    const int row_ = h_ * 128 + ((wid >> 2) * 64) + (nh) * 32 + (wid & 3) * 8 + srow; \
    gl_lds16(Bg + (size_t)(t) * 64 + (size_t)row_ * K + ((sslot ^ srow) * 8), \
             Bs + (((t) & 1) * 16384) + row_ * 64 + sslot * 8); \
  } } while (0)

#define FRA(buf, mrep, kk) \
  (*(const bf16x8*)(As + (buf) * 16384 + (wm * 128 + (mrep) * 16 + m16) * 64 + \
                    ((((kk) * 4 + quad) ^ m7) * 8)))
#define FRB(buf, nrep, kk) \
  (*(const bf16x8*)(Bs + (buf) * 16384 + (wn * 64 + (nrep) * 16 + m16) * 64 + \
                    ((((kk) * 4 + quad) ^ m7) * 8)))

#define LDA4(dst, buf, mh) do { \
  _Pragma("unroll") for (int m4_ = 0; m4_ < 4; ++m4_) { \
    dst[m4_][0] = FRA(buf, (mh) * 4 + m4_, 0); \
    dst[m4_][1] = FRA(buf, (mh) * 4 + m4_, 1); } } while (0)

#define LDB2(dst, buf, nh) do { \
  _Pragma("unroll") for (int n2_ = 0; n2_ < 2; ++n2_) { \
    dst[n2_][0] = FRB(buf, (nh) * 2 + n2_, 0); \
    dst[n2_][1] = FRB(buf, (nh) * 2 + n2_, 1); } } while (0)

#define MMAQ(mh, nh, af, bfm) do { \
  __builtin_amdgcn_s_setprio(1); \
  _Pragma("unroll") for (int kk_ = 0; kk_ < 2; ++kk_) \
  _Pragma("unroll") for (int m4_ = 0; m4_ < 4; ++m4_) \
  _Pragma("unroll") for (int n2_ = 0; n2_ < 2; ++n2_) \
    acc[(mh) * 4 + m4_][(nh) * 2 + n2_] = __builtin_amdgcn_mfma_f32_16x16x32_bf16( \
        af[m4_][kk_], bfm[n2_][kk_], acc[(mh) * 4 + m4_][(nh) * 2 + n2_], 0, 0, 0); \
  __builtin_amdgcn_s_setprio(0); \
} while (0)

__device__ __forceinline__ void gemm8_core(const bf16_t* __restrict__ A,
                                           const bf16_t* __restrict__ B,
                                           const int K, const int tileM, const int tileN,
                                           bf16_t* __restrict__ As, bf16_t* __restrict__ Bs,
                                           f32x4 acc[8][4]) {
  const int tid = threadIdx.x, lane = tid & 63, wid = tid >> 6;
  const int wm = wid >> 2, wn = wid & 3;
  const int quad = lane >> 4, m16 = lane & 15, m7 = lane & 7;
  const int srow = lane >> 3, sslot = lane & 7;
  const f32x4 fz = {0.f, 0.f, 0.f, 0.f};
#pragma unroll
  for (int m = 0; m < 8; ++m)
#pragma unroll
    for (int n = 0; n < 4; ++n) acc[m][n] = fz;
  const bf16_t* Ag = A + (size_t)tileM * K;
  const bf16_t* Bg = B + (size_t)tileN * K;
  const int NT = K >> 6;   // K-tiles (even)
  const int NI = NT >> 1;  // iterations (2 K-tiles each)

  bf16x8 afA[4][2], afB[4][2], bfL[2][2], bfH[2][2];

  // prologue: tile0 complete (8 loads), tile1 {A.mh0, B.nh0, A.mh1} (6 loads);
  // tile1.B.nh1 is staged at iter0 ph1 per the steady-state pattern.
  STA_(0, 0); STA_(0, 1); STB_(0, 0); STB_(0, 1);
  STA_(1, 0); STB_(1, 0); STA_(1, 1);
  VMW(6);  // tile0's 8 loads landed; tile1's 6 in flight
  FBAR;

  for (int i = 0; i < NI - 1; ++i) {
    const int t1 = 2 * i + 1, t2 = 2 * i + 2, t3 = 2 * i + 3;
    // ph1: reads A(t0).mh0 + B(t0).nh0
    LDA4(afA, 0, 0); LDB2(bfL, 0, 0);
    STB_(t1, 1);
    FBAR;
    MMAQ(0, 0, afA, bfL);
    FBAR;
    // ph2: reads B(t0).nh1
    LDB2(bfH, 0, 1);
    STA_(t2, 0);
    FBAR;
    MMAQ(0, 1, afA, bfH);
    FBAR;
    // ph3: reads A(t0).mh1
    LDA4(afB, 0, 1);
    STB_(t2, 0);
    FBAR;
    MMAQ(1, 1, afB, bfH);
    FBAR;
    // ph4: no reads (afB, bfL live in regs)
    STB_(t2, 1);
    VMW(6);  // everything up to ph1's stage landed -> tile t1 ready
    FBAR;
    MMAQ(1, 0, afB, bfL);
    FBAR;
    // ph5: reads A(t1).mh0 + B(t1).nh0
    LDA4(afA, 1, 0); LDB2(bfL, 1, 0);
    STA_(t2, 1);
    FBAR;
    MMAQ(0, 0, afA, bfL);
    FBAR;
    // ph6: reads B(t1).nh1
    LDB2(bfH, 1, 1);
    STA_(t3, 0);
    FBAR;
    MMAQ(0, 1, afA, bfH);
    FBAR;
    // ph7: reads A(t1).mh1
    LDA4(afB, 1, 1);
    STB_(t3, 0);
    FBAR;
    MMAQ(1, 1, afB, bfH);
    FBAR;
    // ph8: no reads
    STA_(t3, 1);
    VMW(6);  // everything up to ph5's stage landed -> tile t2 ready
    FBAR;
    MMAQ(1, 0, afB, bfL);
    FBAR;
  }
  // peeled last iteration (tiles NT-2 / NT-1): only ph1's stage remains
  {
    LDA4(afA, 0, 0); LDB2(bfL, 0, 0);
    STB_(NT - 1, 1);
    FBAR;
    MMAQ(0, 0, afA, bfL);
    FBAR;
    LDB2(bfH, 0, 1);
    FBAR;
    MMAQ(0, 1, afA, bfH);
    FBAR;
    LDA4(afB, 0, 1);
    FBAR;
    MMAQ(1, 1, afB, bfH);
    FBAR;
    VMW(0);  // drain: tile NT-1 fully landed
    FBAR;
    MMAQ(1, 0, afB, bfL);
    FBAR;
    LDA4(afA, 1, 0); LDB2(bfL, 1, 0);
    FBAR;
    MMAQ(0, 0, afA, bfL);
    FBAR;
    LDB2(bfH, 1, 1);
    FBAR;
    MMAQ(0, 1, afA, bfH);
    FBAR;
    LDA4(afB, 1, 1);
    FBAR;
    MMAQ(1, 1, afB, bfH);
    FBAR;
    MMAQ(1, 0, afB, bfL);
  }
}

// GEMM1: A1(4608x3200) @ B1(21504x3200)^T + b1 -> qkv / vraw / gelu->A2
__global__ __launch_bounds__(512, 2) void k_gemm1(const bf16_t* __restrict__ A1,
                                                  const bf16_t* __restrict__ B1,
                                                  const float* __restrict__ b1,
                                                  bf16_t* __restrict__ qkv,
                                                  bf16_t* __restrict__ vraw,
                                                  bf16_t* __restrict__ A2) {
  __shared__ __align__(16) bf16_t As[2 * 256 * 64];
  __shared__ __align__(16) bf16_t Bs[2 * 256 * 64];
  f32x4 acc[8][4];
  const int nwg = 18 * 84;
  const int b = blockIdx.x;
  const int swz = (b & 7) * (nwg >> 3) + (b >> 3);  // bijective XCD swizzle
  const int tileM = (swz % 18) * 256, tileN = (swz / 18) * 256;
  gemm8_core(A1, B1, K1P, tileM, tileN, As, Bs, acc);
  const int lane = threadIdx.x & 63, wid = threadIdx.x >> 6;
  const int wm = wid >> 2, wn = wid & 3;
  const int quad = lane >> 4, m16 = lane & 15;
#pragma unroll
  for (int m = 0; m < 8; ++m) {
    const int row0 = tileM + wm * 128 + m * 16 + quad * 4;
#pragma unroll
    for (int n = 0; n < 4; ++n) {
      const int col = tileN + wn * 64 + n * 16 + m16;
      const float bias = b1[col];
#pragma unroll
      for (int r = 0; r < 4; ++r) {
        const float v = acc[m][n][r] + bias;
        const int rr = row0 + r;
        if (col < 6144) {
          nt_store_bf16(qkv + (size_t)rr * 6144 + col, (bf16_t)v);
        } else if (col < 9216) {
          nt_store_bf16(vraw + (size_t)rr * HIDC + (col - 6144), (bf16_t)v);
        } else {
          nt_store_bf16(A2 + (size_t)rr * K2P + HIDC + (col - 9216), (bf16_t)gelu_tanh(v));
        }
      }
    }
  }
}

// GEMM2: A2(4608x15488) @ B2(3072x15488)^T + b2, out = x + gate*val (fp32)
__global__ __launch_bounds__(512, 2) void k_gemm2(const bf16_t* __restrict__ A2,
                                                  const bf16_t* __restrict__ B2,
                                                  const float* __restrict__ b2,
                                                  const float* __restrict__ x,
                                                  const float* __restrict__ mod,
                                                  float* __restrict__ out) {
  __shared__ __align__(16) bf16_t As[2 * 256 * 64];
  __shared__ __align__(16) bf16_t Bs[2 * 256 * 64];
  f32x4 acc[8][4];
  const int nwg = 18 * 12;
  const int b = blockIdx.x;
  const int swz = (b & 7) * (nwg >> 3) + (b >> 3);
  const int tileM = (swz % 18) * 256, tileN = (swz / 18) * 256;
  gemm8_core(A2, B2, K2P, tileM, tileN, As, Bs, acc);
  const int lane = threadIdx.x & 63, wid = threadIdx.x >> 6;
  const int wm = wid >> 2, wn = wid & 3;
  const int quad = lane >> 4, m16 = lane & 15;
#pragma unroll
  for (int m = 0; m < 8; ++m) {
    const int row0 = tileM + wm * 128 + m * 16 + quad * 4;
#pragma unroll
    for (int n = 0; n < 4; ++n) {
      const int col = tileN + wn * 64 + n * 16 + m16;
      const float bias = b2[col];
      const float gate = mod[2 * HIDC + col];
#pragma unroll
      for (int r = 0; r < 4; ++r) {
        const int rr = row0 + r;
        const float v = acc[m][n][r] + bias;
        __builtin_nontemporal_store(x[(size_t)rr * HIDC + col] + gate * v,
                                    out + (size_t)rr * HIDC + col);
      }
    }
  }
}

// ---------------------------------------------------------------------------
// v transpose: vraw (4608 x 3072, [l][h*128+d]) -> vt (3072 x 4608, [h*128+d][l])
__global__ __launch_bounds__(256) void k_vtrans(const bf16_t* __restrict__ vraw,
                                                bf16_t* __restrict__ vt) {
  __shared__ bf16_t Ts[64][68];
  const int tid = threadIdx.x;
  const int l0 = (blockIdx.x % 72) * 64, c0 = (blockIdx.x / 72) * 64;
#pragma unroll
  for (int s = 0; s < 2; ++s) {
    const int idx = s * 256 + tid;
    const int lrow = idx >> 3, c8 = (idx & 7) * 8;
    bf16x8 v = *(const bf16x8*)(vraw + (size_t)(l0 + lrow) * HIDC + c0 + c8);
#pragma unroll
    for (int e = 0; e < 8; ++e) Ts[c8 + e][lrow] = v[e];
  }
  __syncthreads();
#pragma unroll
  for (int s = 0; s < 2; ++s) {
    const int idx = s * 256 + tid;
    const int drow = idx >> 3, l8 = (idx & 7) * 8;
    bf16x8 v;
#pragma unroll
    for (int e = 0; e < 8; ++e) v[e] = Ts[drow][l8 + e];
    *(bf16x8*)(vt + (size_t)(c0 + drow) * SEQ + l0 + l8) = v;
  }
}

// ---------------------------------------------------------------------------
// RMSNorm + RoPE + repack: one wave per (token, head, q-or-k)
__global__ __launch_bounds__(256) void k_qkprep(const bf16_t* __restrict__ qkv,
                                                const float* __restrict__ pe,
                                                const float* __restrict__ rqw,
                                                const float* __restrict__ rkw,
                                                bf16_t* __restrict__ qp,
                                                bf16_t* __restrict__ kp) {
  const int lane = threadIdx.x & 63, wid = threadIdx.x >> 6;
  int g = blockIdx.x * 4 + wid;
  const int which = (g >= SEQ * NHEAD) ? 1 : 0;
  g -= which * SEQ * NHEAD;
  const int l = g / NHEAD, h = g % NHEAD;
  const int d0 = lane * 2;
  const bf16_t* src = qkv + (size_t)l * 6144 + which * HIDC + h * HDIM + d0;
  bf16x2 xv = *(const bf16x2*)src;
  float x0 = (float)xv[0], x1 = (float)xv[1];
  float ss = x0 * x0 + x1 * x1;
#pragma unroll
  for (int o = 32; o; o >>= 1) ss += __shfl_xor(ss, o);
  const float rstd = rsqrtf(ss * (1.f / HDIM) + 1e-6f);
  const float* wv = which ? rkw : rqw;
  x0 *= rstd * wv[d0];
  x1 *= rstd * wv[d0 + 1];
  const float4 rr = *(const float4*)(pe + (size_t)l * 256 + lane * 4);  // r00 r01 r10 r11
  bf16x2 o2 = {(bf16_t)(rr.x * x0 + rr.y * x1), (bf16_t)(rr.z * x0 + rr.w * x1)};
  bf16_t* dst = (which ? kp : qp) + (size_t)(h * SEQ + l) * HDIM + d0;
  *(bf16x2*)dst = o2;
}

// ---------------------------------------------------------------------------
// Flash attention: block = (head, 64 q-rows), wave = 16 q-rows, K/V tiles of 64
__global__ __launch_bounds__(256, 2) void k_attn(const bf16_t* __restrict__ qp,
                                                 const bf16_t* __restrict__ kp,
                                                 const bf16_t* __restrict__ vt,
                                                 bf16_t* __restrict__ A2) {
  __shared__ __align__(16) bf16_t Ks[16 * 64 * 8];   // [dchunk16][key64][8]
  __shared__ __align__(16) bf16_t Vs[8 * 128 * 8];   // [kchunk8][d128][8]
  __shared__ __align__(16) bf16_t Ps[4][1024];       // per wave [kchunk8][row16][8]
  const float SM_SCALE = 0.08838834764831845f;       // 1/sqrt(128)
  const int tid = threadIdx.x, lane = tid & 63, wid = tid >> 6;
  const int quad = lane >> 4, m16 = lane & 15;
  const int h = blockIdx.x / 72, qt = blockIdx.x % 72;
  const int qbase = qt * 64 + wid * 16;
  bf16x8 qf[4];
  {
    const bf16_t* qr = qp + (size_t)(h * SEQ + qbase + m16) * HDIM + quad * 8;
#pragma unroll
    for (int c = 0; c < 4; ++c) qf[c] = *(const bf16x8*)(qr + c * 32);
  }
  const f32x4 fzero = {0.f, 0.f, 0.f, 0.f};
  f32x4 oacc[8];
#pragma unroll
  for (int j2 = 0; j2 < 8; ++j2) oacc[j2] = fzero;
  float mrun[4] = {-1e30f, -1e30f, -1e30f, -1e30f};
  float lrun[4] = {0.f, 0.f, 0.f, 0.f};
  const bf16_t* kg = kp + (size_t)h * SEQ * HDIM;
  const bf16_t* vg = vt + (size_t)h * HDIM * SEQ;
  for (int kt = 0; kt < SEQ; kt += 64) {
    __syncthreads();
#pragma unroll
    for (int s = 0; s < 4; ++s) {
      int o = s * 256 + tid;
      gl_lds16(kg + (size_t)(kt + (o & 63)) * HDIM + (o >> 6) * 8, Ks + (size_t)o * 8);
    }
#pragma unroll
    for (int s = 0; s < 4; ++s) {
      int o = s * 256 + tid;
      gl_lds16(vg + (size_t)(o & 127) * SEQ + kt + (o >> 7) * 8, Vs + (size_t)o * 8);
    }
    __syncthreads();
    f32x4 st[4];
#pragma unroll
    for (int jj = 0; jj < 4; ++jj) st[jj] = fzero;
    __builtin_amdgcn_s_setprio(1);
#pragma unroll
    for (int c = 0; c < 4; ++c)
#pragma unroll
      for (int jj = 0; jj < 4; ++jj) {
        bf16x8 kf = *(const bf16x8*)(Ks + (size_t)((c * 4 + quad) * 64 + jj * 16 + m16) * 8);
        st[jj] = __builtin_amdgcn_mfma_f32_16x16x32_bf16(qf[c], kf, st[jj], 0, 0, 0);
      }
    __builtin_amdgcn_s_setprio(0);
    float mnew[4], alpha[4], rsum[4];
#pragma unroll
    for (int r = 0; r < 4; ++r) {
      float mx = fmaxf(fmaxf(st[0][r], st[1][r]), fmaxf(st[2][r], st[3][r]));
#pragma unroll
      for (int o = 1; o < 16; o <<= 1) mx = fmaxf(mx, __shfl_xor(mx, o));
      mx *= SM_SCALE;
      float mn = fmaxf(mrun[r], mx);
      alpha[r] = __expf(mrun[r] - mn);
      mnew[r] = mn;
      mrun[r] = mn;
      rsum[r] = 0.f;
    }
#pragma unroll
    for (int jj = 0; jj < 4; ++jj) {
#pragma unroll
      for (int r = 0; r < 4; ++r) {
        float p = __expf(st[jj][r] * SM_SCALE - mnew[r]);
        rsum[r] += p;
        Ps[wid][(size_t)((jj * 2 + (m16 >> 3)) * 16 + quad * 4 + r) * 8 + (m16 & 7)] = (bf16_t)p;
      }
    }
#pragma unroll
    for (int r = 0; r < 4; ++r) {
      float t = rsum[r];
#pragma unroll
      for (int o = 1; o < 16; o <<= 1) t += __shfl_xor(t, o);
      lrun[r] = lrun[r] * alpha[r] + t;
    }
#pragma unroll
    for (int j2 = 0; j2 < 8; ++j2)
#pragma unroll
      for (int r = 0; r < 4; ++r) oacc[j2][r] *= alpha[r];
    __builtin_amdgcn_s_setprio(1);
#pragma unroll
    for (int kc2 = 0; kc2 < 2; ++kc2) {
      bf16x8 pf = *(const bf16x8*)(&Ps[wid][(size_t)((kc2 * 4 + quad) * 16 + m16) * 8]);
#pragma unroll
      for (int j2 = 0; j2 < 8; ++j2) {
        bf16x8 vf = *(const bf16x8*)(Vs + (size_t)((kc2 * 4 + quad) * 128 + j2 * 16 + m16) * 8);
        oacc[j2] = __builtin_amdgcn_mfma_f32_16x16x32_bf16(pf, vf, oacc[j2], 0, 0, 0);
      }
    }
    __builtin_amdgcn_s_setprio(0);
  }
#pragma unroll
  for (int j2 = 0; j2 < 8; ++j2) {
#pragma unroll
    for (int r = 0; r < 4; ++r) {
      const int row = qbase + quad * 4 + r;
      const int col = h * HDIM + j2 * 16 + m16;
      nt_store_bf16(A2 + (size_t)row * K2P + col, (bf16_t)(oacc[j2][r] / lrun[r]));
    }
  }
}

// ---------------------------------------------------------------------------
extern "C" void kernel_launch(void* const* d_in, const int* in_sizes, int n_in,
                              void* d_out, int out_size, void* d_ws, size_t ws_size,
                              hipStream_t stream) {
  const float* x = (const float*)d_in[0];
  const float* vec = (const float*)d_in[1];
  const float* pe = (const float*)d_in[2];
  const float* mod_w = (const float*)d_in[3];
  const float* mod_b = (const float*)d_in[4];
  const float* w1 = (const float*)d_in[5];
  const float* b1 = (const float*)d_in[6];
  const float* ld1 = (const float*)d_in[7];
  const float* lu1 = (const float*)d_in[8];
  const float* w2 = (const float*)d_in[9];
  const float* b2 = (const float*)d_in[10];
  const float* ld2 = (const float*)d_in[11];
  const float* lu2 = (const float*)d_in[12];
  const float* rqw = (const float*)d_in[13];
  const float* rkw = (const float*)d_in[14];
  float* out = (float*)d_out;
  char* ws = (char*)d_ws;

  const size_t OFF_A1 = 36864;
  const size_t OFF_B = OFF_A1 + (size_t)SEQ * K1P * 2;
  const size_t OFF_QKV = OFF_B + (size_t)D1 * K1P * 2;
  const size_t OFF_QP = OFF_QKV + (size_t)SEQ * 6144 * 2;
  const size_t OFF_KP = OFF_QP + (size_t)NHEAD * SEQ * HDIM * 2;
  const size_t OFF_VT = OFF_KP + (size_t)NHEAD * SEQ * HDIM * 2;
  const size_t OFF_A2 = OFF_VT + (size_t)NHEAD * SEQ * HDIM * 2;

  float* mod = (float*)ws;
  bf16_t* A1 = (bf16_t*)(ws + OFF_A1);
  bf16_t* Bw = (bf16_t*)(ws + OFF_B);
  bf16_t* qkv = (bf16_t*)(ws + OFF_QKV);
  bf16_t* qp = (bf16_t*)(ws + OFF_QP);
  bf16_t* vraw = (bf16_t*)(ws + OFF_QP);  // overlays qp/kp until k_qkprep runs
  bf16_t* kp = (bf16_t*)(ws + OFF_KP);
  bf16_t* vt = (bf16_t*)(ws + OFF_VT);
  bf16_t* A2 = (bf16_t*)(ws + OFF_A2);
  // low-rank scratch overlays the qkv region while it is dead:
  //  - before k_gemm1 (qkv not yet written)
  //  - after k_attn (qkv consumed by k_qkprep)
  bf16_t* ldb = (bf16_t*)(ws + OFF_QKV);                  // 32 x K bf16 (<=983 KB)
  float* tpart = (float*)(ws + OFF_QKV + (1u << 20));     // LRKS x 4608 x 32 f32 (9.4 MB)

  k_convB<<<D1, 256, 0, stream>>>(w1, lu1, Bw, HIDC, K1P);
  k_convB<<<32, 256, 0, stream>>>(ld1, ld1, ldb, HIDC, HIDC);  // ld1 -> bf16
  k_mod<<<9216 / 4, 256, 0, stream>>>(vec, mod_w, mod_b, mod);
  k_ln<<<SEQ, 256, 0, stream>>>(x, mod, A1);
  k_lr1<<<72 * LRKS, 256, 0, stream>>>(A1, ldb, tpart, HIDC, K1P, HIDC / LRKS);
  k_lr2<<<SEQ / 8, 256, 0, stream>>>(tpart, A1, HIDC, K1P);
  k_gemm1<<<18 * 84, 512, 0, stream>>>(A1, Bw, b1, qkv, vraw, A2);
  k_vtrans<<<72 * 48, 256, 0, stream>>>(vraw, vt);
  k_qkprep<<<SEQ * NHEAD * 2 / 4, 256, 0, stream>>>(qkv, pe, rqw, rkw, qp, kp);
  k_attn<<<NHEAD * 72, 256, 0, stream>>>(qp, kp, vt, A2);
  k_convB<<<HIDC, 256, 0, stream>>>(w2, lu2, Bw, K2DIM, K2P);
  k_convB<<<32, 256, 0, stream>>>(ld2, ld2, ldb, K2DIM, K2DIM);  // ld2 -> bf16
  k_lr1<<<72 * LRKS, 256, 0, stream>>>(A2, ldb, tpart, K2DIM, K2P, K2DIM / LRKS);
  k_lr2<<<SEQ / 8, 256, 0, stream>>>(tpart, A2, K2DIM, K2P);
  k_gemm2<<<18 * 12, 512, 0, stream>>>(A2, Bw, b2, x, mod, out);
}